// Round 1
// baseline (190.109 us; speedup 1.0000x reference)
//
#include <hip/hip_runtime.h>
#include <math.h>

#define HIDDEN 1024
#define NSTATE 16
#define DTRANK 64
#define BB 2
#define SS 2048
#define ROWS (BB*SS)            // 4096
#define XPC 96                  // 2*STATE + DT_RANK
#define CH 64                   // number of chunks along S
#define CL 32                   // chunk length (CH*CL == SS)
#define BND (BB*NSTATE*HIDDEN)  // 32768
#define LOG2E 1.44269504088896f

// ---------------- K1: xp = x @ W_xproj  (4096 x 96) ----------------
// block 256 = 8 rows x 32 cols; grid (512, 3)
__global__ void k_xproj(const float* __restrict__ x, const float* __restrict__ W,
                        float* __restrict__ xp) {
    int rloc = threadIdx.x >> 5;
    int cloc = threadIdx.x & 31;
    int r = blockIdx.x * 8 + rloc;
    int c = blockIdx.y * 32 + cloc;
    const float* xr = x + r * HIDDEN;
    float acc = 0.f;
    #pragma unroll 4
    for (int k = 0; k < HIDDEN; k += 4) {
        float4 xv = *(const float4*)(xr + k);
        acc = fmaf(xv.x, W[(k+0)*XPC + c], acc);
        acc = fmaf(xv.y, W[(k+1)*XPC + c], acc);
        acc = fmaf(xv.z, W[(k+2)*XPC + c], acc);
        acc = fmaf(xv.w, W[(k+3)*XPC + c], acc);
    }
    xp[r * XPC + c] = acc;
}

// ---------------- K2: dt = softplus(xp[:,32:96] @ W_dt + b_dt) ----------------
// one block per row; 256 threads, 4 cols each
__global__ void k_dt(const float* __restrict__ xp, const float* __restrict__ Wdt,
                     const float* __restrict__ bdt, float* __restrict__ dt) {
    __shared__ float lx[DTRANK];
    int r = blockIdx.x;
    int tid = threadIdx.x;
    if (tid < 16) {
        *(float4*)&lx[tid*4] = *(const float4*)&xp[r*XPC + 2*NSTATE + tid*4];
    }
    __syncthreads();
    int j = tid * 4;
    float4 acc = *(const float4*)&bdt[j];
    #pragma unroll 8
    for (int t = 0; t < DTRANK; ++t) {
        float s = lx[t];
        float4 w = *(const float4*)&Wdt[t*HIDDEN + j];
        acc.x = fmaf(s, w.x, acc.x);
        acc.y = fmaf(s, w.y, acc.y);
        acc.z = fmaf(s, w.z, acc.z);
        acc.w = fmaf(s, w.w, acc.w);
    }
    float4 o;
    o.x = fmaxf(acc.x, 0.f) + log1pf(__expf(-fabsf(acc.x)));
    o.y = fmaxf(acc.y, 0.f) + log1pf(__expf(-fabsf(acc.y)));
    o.z = fmaxf(acc.z, 0.f) + log1pf(__expf(-fabsf(acc.z)));
    o.w = fmaxf(acc.w, 0.f) + log1pf(__expf(-fabsf(acc.w)));
    *(float4*)&dt[r*HIDDEN + j] = o;
}

// ---------------- K3 (pass 1): per-chunk P = prod(a), Q = local scan end ----------------
// thread = (chunk, b, n, d); block 256 d's; grid = CH*B*N*4 = 8192
__global__ void k_pass1(const float* __restrict__ x, const float* __restrict__ dt,
                        const float* __restrict__ xp, const float* __restrict__ Alog,
                        float* __restrict__ P, float* __restrict__ Q) {
    int bid = blockIdx.x;
    int dblk = bid & 3;
    int n = (bid >> 2) & 15;
    int b = (bid >> 6) & 1;
    int c = bid >> 7;
    int d = dblk * 256 + threadIdx.x;
    float A2 = -__expf(Alog[n*HIDDEN + d]) * LOG2E;   // A * log2(e)
    float Pv = 1.f, Qv = 0.f;
    int s0 = c * CL;
    #pragma unroll 4
    for (int i = 0; i < CL; ++i) {
        int r = b*SS + s0 + i;
        float dv = dt[r*HIDDEN + d];
        float xv = x[r*HIDDEN + d];
        float bm = xp[r*XPC + n];
        float a = exp2f(A2 * dv);
        Qv = fmaf(a, Qv, bm * dv * xv);
        Pv *= a;
    }
    int idx = c*BND + b*(NSTATE*HIDDEN) + n*HIDDEN + d;
    P[idx] = Pv;
    Q[idx] = Qv;
}

// ---------------- K4 (pass 2): serial scan over chunks; P[c] <- h entering chunk c ----------------
__global__ void k_pass2(float* __restrict__ P, const float* __restrict__ Q) {
    int bnd = blockIdx.x * 256 + threadIdx.x;   // < 32768
    float h = 0.f;
    for (int c = 0; c < CH; ++c) {
        int idx = c*BND + bnd;
        float p = P[idx];
        float q = Q[idx];
        P[idx] = h;                 // h_start for chunk c
        h = fmaf(p, h, q);
    }
}

// ---------------- K5 (pass 3): re-run local scan from h_start, emit y ----------------
// thread = (chunk, b, d), all 16 states in registers; grid = CH*B*4 = 512
__global__ void k_pass3(const float* __restrict__ x, const float* __restrict__ dt,
                        const float* __restrict__ xp, const float* __restrict__ Alog,
                        const float* __restrict__ Hs, float* __restrict__ y) {
    int bid = blockIdx.x;
    int dblk = bid & 3;
    int b = (bid >> 2) & 1;
    int c = bid >> 3;
    int d = dblk * 256 + threadIdx.x;

    float A2[NSTATE], h[NSTATE];
    #pragma unroll
    for (int n = 0; n < NSTATE; ++n) {
        A2[n] = -__expf(Alog[n*HIDDEN + d]) * LOG2E;
        h[n] = Hs[c*BND + b*(NSTATE*HIDDEN) + n*HIDDEN + d];
    }
    int s0 = c * CL;
    for (int i = 0; i < CL; ++i) {
        int r = b*SS + s0 + i;
        float dv = dt[r*HIDDEN + d];
        float xv = x[r*HIDDEN + d];
        float bx = dv * xv;
        float bm[NSTATE], cm[NSTATE];
        *(float4*)&bm[0]  = *(const float4*)&xp[r*XPC + 0];
        *(float4*)&bm[4]  = *(const float4*)&xp[r*XPC + 4];
        *(float4*)&bm[8]  = *(const float4*)&xp[r*XPC + 8];
        *(float4*)&bm[12] = *(const float4*)&xp[r*XPC + 12];
        *(float4*)&cm[0]  = *(const float4*)&xp[r*XPC + 16];
        *(float4*)&cm[4]  = *(const float4*)&xp[r*XPC + 20];
        *(float4*)&cm[8]  = *(const float4*)&xp[r*XPC + 24];
        *(float4*)&cm[12] = *(const float4*)&xp[r*XPC + 28];
        float yv = 0.f;
        #pragma unroll
        for (int n = 0; n < NSTATE; ++n) {
            float a = exp2f(A2[n] * dv);
            h[n] = fmaf(a, h[n], bm[n] * bx);
            yv = fmaf(cm[n], h[n], yv);
        }
        y[r*HIDDEN + d] = yv;
    }
}

extern "C" void kernel_launch(void* const* d_in, const int* in_sizes, int n_in,
                              void* d_out, int out_size, void* d_ws, size_t ws_size,
                              hipStream_t stream) {
    const float* x    = (const float*)d_in[0];
    const float* Wx   = (const float*)d_in[1];
    const float* Wdt  = (const float*)d_in[2];
    const float* bdt  = (const float*)d_in[3];
    const float* Alog = (const float*)d_in[4];
    float* y  = (float*)d_out;
    float* ws = (float*)d_ws;

    float* xp = ws;                       // 4096*96      = 393216 floats
    float* dt = xp + ROWS*XPC;            // 4096*1024    = 4194304 floats
    float* P  = dt + ROWS*HIDDEN;         // CH*BND       = 2097152 floats
    float* Q  = P + CH*BND;               // CH*BND       = 2097152 floats
    // total ws use: ~33.5 MB

    k_xproj<<<dim3(512, 3), dim3(256), 0, stream>>>(x, Wx, xp);
    k_dt<<<ROWS, 256, 0, stream>>>(xp, Wdt, bdt, dt);
    k_pass1<<<CH*BB*NSTATE*4, 256, 0, stream>>>(x, dt, xp, Alog, P, Q);
    k_pass2<<<BND/256, 256, 0, stream>>>(P, Q);
    k_pass3<<<CH*BB*4, 256, 0, stream>>>(x, dt, xp, Alog, P, y);
}

// Round 2
// 122.527 us; speedup vs baseline: 1.5516x; 1.5516x over previous
//
#include <hip/hip_runtime.h>
#include <math.h>

#define HIDDEN 1024
#define NSTATE 16
#define DTRANK 64
#define BB 2
#define SS 2048
#define ROWS (BB*SS)            // 4096
#define XPC 96                  // 2*STATE + DT_RANK
#define CH 64                   // number of chunks along S
#define CL 32                   // chunk length (CH*CL == SS)
#define BND (BB*NSTATE*HIDDEN)  // 32768
#define LOG2E 1.44269504088896f

#define RT 128                  // rows per k1 block
#define KSPL 8                  // K splits in k1

// ---------------- K1: partial xp = x @ W_xproj, K-split ----------------
// grid 256 = 32 row-tiles x 8 k-splits; block 256 (16 col-groups x 16 row-groups)
// each thread: 8 rows x 6 cols (cols cg+16j) over K range of 128.
__global__ void k_xproj2(const float* __restrict__ x, const float* __restrict__ W,
                         float* __restrict__ part) {
    __shared__ float xs[RT * 32];      // [row][kb^swz] float4 blocks, 16KB
    __shared__ float wt[96 * 36];      // transposed W [c][k], stride 36, 13.5KB
    int t  = threadIdx.x;
    int rt = blockIdx.x >> 3;
    int ks = blockIdx.x & 7;
    int r0 = rt * RT;
    int k0 = ks * 128;
    int cg = t & 15, rg = t >> 4;

    float acc[8][6];
    #pragma unroll
    for (int a = 0; a < 8; ++a)
        #pragma unroll
        for (int b = 0; b < 6; ++b) acc[a][b] = 0.f;

    for (int ch = 0; ch < 4; ++ch) {
        int kc = k0 + ch * 32;
        __syncthreads();
        // stage x tile: 128 rows x 32 k, swizzled 16B blocks
        #pragma unroll
        for (int m = 0; m < 4; ++m) {
            int e = t + m * 256;
            int row = e >> 3, kb = e & 7;
            float4 v = *(const float4*)&x[(r0 + row) * HIDDEN + kc + kb * 4];
            int kbp = kb ^ ((row >> 3) & 7);
            *(float4*)&xs[row * 32 + kbp * 4] = v;
        }
        // stage W tile transposed: 32 k x 96 c -> wt[c][k]
        #pragma unroll
        for (int m = 0; m < 3; ++m) {
            int f = t + m * 256;
            int kr = f / 24, cq = f % 24;
            float4 v = *(const float4*)&W[(kc + kr) * XPC + cq * 4];
            wt[(cq * 4 + 0) * 36 + kr] = v.x;
            wt[(cq * 4 + 1) * 36 + kr] = v.y;
            wt[(cq * 4 + 2) * 36 + kr] = v.z;
            wt[(cq * 4 + 3) * 36 + kr] = v.w;
        }
        __syncthreads();
        #pragma unroll
        for (int kg = 0; kg < 8; ++kg) {
            float4 wv[6], xv[8];
            #pragma unroll
            for (int j = 0; j < 6; ++j)
                wv[j] = *(float4*)&wt[(cg + 16 * j) * 36 + kg * 4];
            #pragma unroll
            for (int rr = 0; rr < 8; ++rr)
                xv[rr] = *(float4*)&xs[(rg * 8 + rr) * 32 + ((kg ^ (rg & 7)) * 4)];
            #pragma unroll
            for (int rr = 0; rr < 8; ++rr)
                #pragma unroll
                for (int j = 0; j < 6; ++j) {
                    acc[rr][j] = fmaf(xv[rr].x, wv[j].x, acc[rr][j]);
                    acc[rr][j] = fmaf(xv[rr].y, wv[j].y, acc[rr][j]);
                    acc[rr][j] = fmaf(xv[rr].z, wv[j].z, acc[rr][j]);
                    acc[rr][j] = fmaf(xv[rr].w, wv[j].w, acc[rr][j]);
                }
        }
    }
    #pragma unroll
    for (int rr = 0; rr < 8; ++rr)
        #pragma unroll
        for (int j = 0; j < 6; ++j)
            part[ks * (ROWS * XPC) + (r0 + rg * 8 + rr) * XPC + cg + 16 * j] = acc[rr][j];
}

// ---------------- K1b: reduce K-split partials ----------------
__global__ void k_reduce(const float* __restrict__ part, float* __restrict__ xp) {
    int i = blockIdx.x * 256 + threadIdx.x;   // < ROWS*XPC
    float s = 0.f;
    #pragma unroll
    for (int p = 0; p < KSPL; ++p) s += part[p * (ROWS * XPC) + i];
    xp[i] = s;
}

// ---------------- K2: dt = softplus(xp[:,32:96] @ W_dt + b_dt) ----------------
// 8 rows per block; 512 blocks; each thread: 8 rows x 4 cols
__global__ void k_dt2(const float* __restrict__ xp, const float* __restrict__ Wdt,
                      const float* __restrict__ bdt, float* __restrict__ dt) {
    __shared__ float xs[8 * 64];
    int t = threadIdx.x;
    int r0 = blockIdx.x * 8;
    if (t < 128) {
        int row = t >> 4, kq = t & 15;
        *(float4*)&xs[row * 64 + kq * 4] =
            *(const float4*)&xp[(r0 + row) * XPC + 2 * NSTATE + kq * 4];
    }
    __syncthreads();
    float4 acc[8];
    float4 b = *(const float4*)&bdt[t * 4];
    #pragma unroll
    for (int rr = 0; rr < 8; ++rr) acc[rr] = b;
    #pragma unroll 4
    for (int k = 0; k < DTRANK; ++k) {
        float4 w = *(const float4*)&Wdt[k * HIDDEN + t * 4];
        #pragma unroll
        for (int rr = 0; rr < 8; ++rr) {
            float s = xs[rr * 64 + k];
            acc[rr].x = fmaf(s, w.x, acc[rr].x);
            acc[rr].y = fmaf(s, w.y, acc[rr].y);
            acc[rr].z = fmaf(s, w.z, acc[rr].z);
            acc[rr].w = fmaf(s, w.w, acc[rr].w);
        }
    }
    #pragma unroll
    for (int rr = 0; rr < 8; ++rr) {
        float4 a = acc[rr], o;
        o.x = fmaxf(a.x, 0.f) + log1pf(__expf(-fabsf(a.x)));
        o.y = fmaxf(a.y, 0.f) + log1pf(__expf(-fabsf(a.y)));
        o.z = fmaxf(a.z, 0.f) + log1pf(__expf(-fabsf(a.z)));
        o.w = fmaxf(a.w, 0.f) + log1pf(__expf(-fabsf(a.w)));
        *(float4*)&dt[(r0 + rr) * HIDDEN + t * 4] = o;
    }
}

// ---------------- K3 (pass 1): per-chunk P = prod(a), Q = local scan end ----------------
__global__ void k_pass1(const float* __restrict__ x, const float* __restrict__ dt,
                        const float* __restrict__ xp, const float* __restrict__ Alog,
                        float* __restrict__ P, float* __restrict__ Q) {
    int bid = blockIdx.x;
    int dblk = bid & 3;
    int n = (bid >> 2) & 15;
    int b = (bid >> 6) & 1;
    int c = bid >> 7;
    int d = dblk * 256 + threadIdx.x;
    float A2 = -__expf(Alog[n*HIDDEN + d]) * LOG2E;   // A * log2(e)
    float Pv = 1.f, Qv = 0.f;
    int s0 = c * CL;
    #pragma unroll 4
    for (int i = 0; i < CL; ++i) {
        int r = b*SS + s0 + i;
        float dv = dt[r*HIDDEN + d];
        float xv = x[r*HIDDEN + d];
        float bm = xp[r*XPC + n];
        float a = exp2f(A2 * dv);
        Qv = fmaf(a, Qv, bm * dv * xv);
        Pv *= a;
    }
    int idx = c*BND + b*(NSTATE*HIDDEN) + n*HIDDEN + d;
    P[idx] = Pv;
    Q[idx] = Qv;
}

// ---------------- K4 (pass 2): serial scan over chunks ----------------
__global__ void k_pass2(float* __restrict__ P, const float* __restrict__ Q) {
    int bnd = blockIdx.x * 256 + threadIdx.x;   // < 32768
    float h = 0.f;
    for (int c = 0; c < CH; ++c) {
        int idx = c*BND + bnd;
        float p = P[idx];
        float q = Q[idx];
        P[idx] = h;                 // h_start for chunk c
        h = fmaf(p, h, q);
    }
}

// ---------------- K5 (pass 3): re-run local scan from h_start, emit y ----------------
__global__ void k_pass3(const float* __restrict__ x, const float* __restrict__ dt,
                        const float* __restrict__ xp, const float* __restrict__ Alog,
                        const float* __restrict__ Hs, float* __restrict__ y) {
    int bid = blockIdx.x;
    int dblk = bid & 3;
    int b = (bid >> 2) & 1;
    int c = bid >> 3;
    int d = dblk * 256 + threadIdx.x;

    float A2[NSTATE], h[NSTATE];
    #pragma unroll
    for (int n = 0; n < NSTATE; ++n) {
        A2[n] = -__expf(Alog[n*HIDDEN + d]) * LOG2E;
        h[n] = Hs[c*BND + b*(NSTATE*HIDDEN) + n*HIDDEN + d];
    }
    int s0 = c * CL;
    for (int i = 0; i < CL; ++i) {
        int r = b*SS + s0 + i;
        float dv = dt[r*HIDDEN + d];
        float xv = x[r*HIDDEN + d];
        float bx = dv * xv;
        float bm[NSTATE], cm[NSTATE];
        *(float4*)&bm[0]  = *(const float4*)&xp[r*XPC + 0];
        *(float4*)&bm[4]  = *(const float4*)&xp[r*XPC + 4];
        *(float4*)&bm[8]  = *(const float4*)&xp[r*XPC + 8];
        *(float4*)&bm[12] = *(const float4*)&xp[r*XPC + 12];
        *(float4*)&cm[0]  = *(const float4*)&xp[r*XPC + 16];
        *(float4*)&cm[4]  = *(const float4*)&xp[r*XPC + 20];
        *(float4*)&cm[8]  = *(const float4*)&xp[r*XPC + 24];
        *(float4*)&cm[12] = *(const float4*)&xp[r*XPC + 28];
        float yv = 0.f;
        #pragma unroll
        for (int n = 0; n < NSTATE; ++n) {
            float a = exp2f(A2[n] * dv);
            h[n] = fmaf(a, h[n], bm[n] * bx);
            yv = fmaf(cm[n], h[n], yv);
        }
        y[r*HIDDEN + d] = yv;
    }
}

extern "C" void kernel_launch(void* const* d_in, const int* in_sizes, int n_in,
                              void* d_out, int out_size, void* d_ws, size_t ws_size,
                              hipStream_t stream) {
    const float* x    = (const float*)d_in[0];
    const float* Wx   = (const float*)d_in[1];
    const float* Wdt  = (const float*)d_in[2];
    const float* bdt  = (const float*)d_in[3];
    const float* Alog = (const float*)d_in[4];
    float* y  = (float*)d_out;
    float* ws = (float*)d_ws;

    float* xp = ws;                       // 393216 floats
    float* dt = xp + ROWS*XPC;            // 4194304 floats
    float* A  = dt + ROWS*HIDDEN;         // alias region:
    float* part = A;                      //   k1 partials: 8*393216 = 3145728 floats
    float* P  = A;                        //   then P: 2097152
    float* Q  = A + CH*BND;               //   and Q: 2097152
    // total ws use: (393216 + 4194304 + 4194304) * 4B ≈ 35.1 MB

    k_xproj2<<<(ROWS/RT)*KSPL, 256, 0, stream>>>(x, Wx, part);
    k_reduce<<<ROWS*XPC/256, 256, 0, stream>>>(part, xp);
    k_dt2<<<ROWS/8, 256, 0, stream>>>(xp, Wdt, bdt, dt);
    k_pass1<<<CH*BB*NSTATE*4, 256, 0, stream>>>(x, dt, xp, Alog, P, Q);
    k_pass2<<<BND/256, 256, 0, stream>>>(P, Q);
    k_pass3<<<CH*BB*4, 256, 0, stream>>>(x, dt, xp, Alog, P, y);
}

// Round 3
// 119.556 us; speedup vs baseline: 1.5901x; 1.0248x over previous
//
#include <hip/hip_runtime.h>
#include <math.h>

#define HIDDEN 1024
#define NSTATE 16
#define DTRANK 64
#define BB 2
#define SS 2048
#define ROWS (BB*SS)            // 4096
#define XPC 96                  // 2*STATE + DT_RANK
#define CH 128                  // number of chunks along S
#define CL 16                   // chunk length (CH*CL == SS)
#define BND (BB*NSTATE*HIDDEN)  // 32768
#define LOG2E 1.44269504088896f

#define RT 128                  // rows per k1 block
#define KSPL 8                  // K splits in k1

// ---------------- K1: partial xp = x @ W_xproj, K-split ----------------
__global__ void k_xproj2(const float* __restrict__ x, const float* __restrict__ W,
                         float* __restrict__ part) {
    __shared__ float xs[RT * 32];      // [row][kb^swz] float4 blocks, 16KB
    __shared__ float wt[96 * 36];      // transposed W [c][k], stride 36, 13.5KB
    int t  = threadIdx.x;
    int rt = blockIdx.x >> 3;
    int ks = blockIdx.x & 7;
    int r0 = rt * RT;
    int k0 = ks * 128;
    int cg = t & 15, rg = t >> 4;

    float acc[8][6];
    #pragma unroll
    for (int a = 0; a < 8; ++a)
        #pragma unroll
        for (int b = 0; b < 6; ++b) acc[a][b] = 0.f;

    for (int ch = 0; ch < 4; ++ch) {
        int kc = k0 + ch * 32;
        __syncthreads();
        #pragma unroll
        for (int m = 0; m < 4; ++m) {
            int e = t + m * 256;
            int row = e >> 3, kb = e & 7;
            float4 v = *(const float4*)&x[(r0 + row) * HIDDEN + kc + kb * 4];
            int kbp = kb ^ ((row >> 3) & 7);
            *(float4*)&xs[row * 32 + kbp * 4] = v;
        }
        #pragma unroll
        for (int m = 0; m < 3; ++m) {
            int f = t + m * 256;
            int kr = f / 24, cq = f % 24;
            float4 v = *(const float4*)&W[(kc + kr) * XPC + cq * 4];
            wt[(cq * 4 + 0) * 36 + kr] = v.x;
            wt[(cq * 4 + 1) * 36 + kr] = v.y;
            wt[(cq * 4 + 2) * 36 + kr] = v.z;
            wt[(cq * 4 + 3) * 36 + kr] = v.w;
        }
        __syncthreads();
        #pragma unroll
        for (int kg = 0; kg < 8; ++kg) {
            float4 wv[6], xv[8];
            #pragma unroll
            for (int j = 0; j < 6; ++j)
                wv[j] = *(float4*)&wt[(cg + 16 * j) * 36 + kg * 4];
            #pragma unroll
            for (int rr = 0; rr < 8; ++rr)
                xv[rr] = *(float4*)&xs[(rg * 8 + rr) * 32 + ((kg ^ (rg & 7)) * 4)];
            #pragma unroll
            for (int rr = 0; rr < 8; ++rr)
                #pragma unroll
                for (int j = 0; j < 6; ++j) {
                    acc[rr][j] = fmaf(xv[rr].x, wv[j].x, acc[rr][j]);
                    acc[rr][j] = fmaf(xv[rr].y, wv[j].y, acc[rr][j]);
                    acc[rr][j] = fmaf(xv[rr].z, wv[j].z, acc[rr][j]);
                    acc[rr][j] = fmaf(xv[rr].w, wv[j].w, acc[rr][j]);
                }
        }
    }
    #pragma unroll
    for (int rr = 0; rr < 8; ++rr)
        #pragma unroll
        for (int j = 0; j < 6; ++j)
            part[ks * (ROWS * XPC) + (r0 + rg * 8 + rr) * XPC + cg + 16 * j] = acc[rr][j];
}

// ---------------- K2: fused reduce(part)->xp  +  dt = softplus(xp_dt @ W_dt + b) ----------------
// 8 rows per block; 512 blocks
__global__ void k_rdt(const float* __restrict__ part, const float* __restrict__ Wdt,
                      const float* __restrict__ bdt, float* __restrict__ xp,
                      float* __restrict__ dt) {
    __shared__ float xs[8 * 64];
    int t = threadIdx.x;
    int r0 = blockIdx.x * 8;
    // reduce 8 rows x 96 cols of K-split partials
    #pragma unroll
    for (int m = 0; m < 3; ++m) {
        int o = t + m * 256;              // 0..767
        int row = o / 96, col = o % 96;
        float s = 0.f;
        #pragma unroll
        for (int p = 0; p < KSPL; ++p)
            s += part[p * (ROWS * XPC) + (r0 + row) * XPC + col];
        xp[(r0 + row) * XPC + col] = s;
        if (col >= 2 * NSTATE) xs[row * 64 + (col - 2 * NSTATE)] = s;
    }
    __syncthreads();
    float4 acc[8];
    float4 b = *(const float4*)&bdt[t * 4];
    #pragma unroll
    for (int rr = 0; rr < 8; ++rr) acc[rr] = b;
    #pragma unroll 4
    for (int k = 0; k < DTRANK; ++k) {
        float4 w = *(const float4*)&Wdt[k * HIDDEN + t * 4];
        #pragma unroll
        for (int rr = 0; rr < 8; ++rr) {
            float s = xs[rr * 64 + k];
            acc[rr].x = fmaf(s, w.x, acc[rr].x);
            acc[rr].y = fmaf(s, w.y, acc[rr].y);
            acc[rr].z = fmaf(s, w.z, acc[rr].z);
            acc[rr].w = fmaf(s, w.w, acc[rr].w);
        }
    }
    #pragma unroll
    for (int rr = 0; rr < 8; ++rr) {
        float4 a = acc[rr], o;
        o.x = fmaxf(a.x, 0.f) + log1pf(__expf(-fabsf(a.x)));
        o.y = fmaxf(a.y, 0.f) + log1pf(__expf(-fabsf(a.y)));
        o.z = fmaxf(a.z, 0.f) + log1pf(__expf(-fabsf(a.z)));
        o.w = fmaxf(a.w, 0.f) + log1pf(__expf(-fabsf(a.w)));
        *(float4*)&dt[(r0 + rr) * HIDDEN + t * 4] = o;
    }
}

// ---------------- K3 (pass 1): thread owns (c,b,d), all 16 states in regs ----------------
// grid = CH*BB*4 = 1024 blocks
__global__ __launch_bounds__(256, 4)
void k_pass1(const float* __restrict__ x, const float* __restrict__ dt,
             const float* __restrict__ xp, const float* __restrict__ Alog,
             float* __restrict__ P, float* __restrict__ Q) {
    int bid = blockIdx.x;
    int dblk = bid & 3;
    int b = (bid >> 2) & 1;
    int c = bid >> 3;
    int d = dblk * 256 + threadIdx.x;
    float A2[NSTATE], Pv[NSTATE], Qv[NSTATE];
    #pragma unroll
    for (int n = 0; n < NSTATE; ++n) {
        A2[n] = -__expf(Alog[n*HIDDEN + d]) * LOG2E;
        Pv[n] = 1.f; Qv[n] = 0.f;
    }
    int s0 = c * CL;
    for (int i = 0; i < CL; ++i) {
        int r = b*SS + s0 + i;
        float dv = dt[r*HIDDEN + d];
        float xv = x[r*HIDDEN + d];
        float bm[NSTATE];
        *(float4*)&bm[0]  = *(const float4*)&xp[r*XPC + 0];
        *(float4*)&bm[4]  = *(const float4*)&xp[r*XPC + 4];
        *(float4*)&bm[8]  = *(const float4*)&xp[r*XPC + 8];
        *(float4*)&bm[12] = *(const float4*)&xp[r*XPC + 12];
        float bx = dv * xv;
        #pragma unroll
        for (int n = 0; n < NSTATE; ++n) {
            float a = exp2f(A2[n] * dv);
            Qv[n] = fmaf(a, Qv[n], bm[n] * bx);
            Pv[n] *= a;
        }
    }
    int base = b*(NSTATE*HIDDEN) + d;
    #pragma unroll
    for (int n = 0; n < NSTATE; ++n) {
        P[c*BND + base + n*HIDDEN] = Pv[n];
        Q[c*BND + base + n*HIDDEN] = Qv[n];
    }
}

// ---------------- K4 (pass 2): serial scan over chunks, 8-deep batched loads ----------------
__global__ void k_pass2(float* __restrict__ P, const float* __restrict__ Q) {
    int bnd = blockIdx.x * 256 + threadIdx.x;   // < 32768
    float h = 0.f;
    for (int cb = 0; cb < CH / 8; ++cb) {
        float p[8], q[8];
        #pragma unroll
        for (int j = 0; j < 8; ++j) {
            int idx = (cb*8 + j)*BND + bnd;
            p[j] = P[idx]; q[j] = Q[idx];
        }
        #pragma unroll
        for (int j = 0; j < 8; ++j) {
            int idx = (cb*8 + j)*BND + bnd;
            P[idx] = h;                 // h_start for chunk
            h = fmaf(p[j], h, q[j]);
        }
    }
}

// ---------------- K5 (pass 3): re-run local scan from h_start, emit y ----------------
// grid = CH*BB*4 = 1024 blocks
__global__ __launch_bounds__(256, 4)
void k_pass3(const float* __restrict__ x, const float* __restrict__ dt,
             const float* __restrict__ xp, const float* __restrict__ Alog,
             const float* __restrict__ Hs, float* __restrict__ y) {
    int bid = blockIdx.x;
    int dblk = bid & 3;
    int b = (bid >> 2) & 1;
    int c = bid >> 3;
    int d = dblk * 256 + threadIdx.x;

    float A2[NSTATE], h[NSTATE];
    #pragma unroll
    for (int n = 0; n < NSTATE; ++n) {
        A2[n] = -__expf(Alog[n*HIDDEN + d]) * LOG2E;
        h[n] = Hs[c*BND + b*(NSTATE*HIDDEN) + n*HIDDEN + d];
    }
    int s0 = c * CL;
    for (int i = 0; i < CL; ++i) {
        int r = b*SS + s0 + i;
        float dv = dt[r*HIDDEN + d];
        float xv = x[r*HIDDEN + d];
        float bx = dv * xv;
        float bm[NSTATE], cm[NSTATE];
        *(float4*)&bm[0]  = *(const float4*)&xp[r*XPC + 0];
        *(float4*)&bm[4]  = *(const float4*)&xp[r*XPC + 4];
        *(float4*)&bm[8]  = *(const float4*)&xp[r*XPC + 8];
        *(float4*)&bm[12] = *(const float4*)&xp[r*XPC + 12];
        *(float4*)&cm[0]  = *(const float4*)&xp[r*XPC + 16];
        *(float4*)&cm[4]  = *(const float4*)&xp[r*XPC + 20];
        *(float4*)&cm[8]  = *(const float4*)&xp[r*XPC + 24];
        *(float4*)&cm[12] = *(const float4*)&xp[r*XPC + 28];
        float yv = 0.f;
        #pragma unroll
        for (int n = 0; n < NSTATE; ++n) {
            float a = exp2f(A2[n] * dv);
            h[n] = fmaf(a, h[n], bm[n] * bx);
            yv = fmaf(cm[n], h[n], yv);
        }
        y[r*HIDDEN + d] = yv;
    }
}

extern "C" void kernel_launch(void* const* d_in, const int* in_sizes, int n_in,
                              void* d_out, int out_size, void* d_ws, size_t ws_size,
                              hipStream_t stream) {
    const float* x    = (const float*)d_in[0];
    const float* Wx   = (const float*)d_in[1];
    const float* Wdt  = (const float*)d_in[2];
    const float* bdt  = (const float*)d_in[3];
    const float* Alog = (const float*)d_in[4];
    float* y  = (float*)d_out;
    float* ws = (float*)d_ws;

    float* xp = ws;                       // 393216 floats
    float* dt = xp + ROWS*XPC;            // 4194304 floats
    float* A  = dt + ROWS*HIDDEN;         // alias region:
    float* part = A;                      //   k1 partials: 3145728 floats (12.6MB)
    float* P  = A;                        //   P: CH*BND = 4194304 floats (16.8MB)
    float* Q  = A + CH*BND;               //   Q: 4194304 floats (16.8MB)
    // total ws use: ~50.3 MB

    k_xproj2<<<(ROWS/RT)*KSPL, 256, 0, stream>>>(x, Wx, part);
    k_rdt<<<ROWS/8, 256, 0, stream>>>(part, Wdt, bdt, xp, dt);
    k_pass1<<<CH*BB*4, 256, 0, stream>>>(x, dt, xp, Alog, P, Q);
    k_pass2<<<BND/256, 256, 0, stream>>>(P, Q);
    k_pass3<<<CH*BB*4, 256, 0, stream>>>(x, dt, xp, Alog, P, y);
}

// Round 4
// 112.370 us; speedup vs baseline: 1.6918x; 1.0640x over previous
//
#include <hip/hip_runtime.h>
#include <math.h>

#define HIDDEN 1024
#define NSTATE 16
#define DTRANK 64
#define BB 2
#define SS 2048
#define ROWS (BB*SS)            // 4096
#define XPC 96                  // 2*STATE + DT_RANK
#define CH 64                   // number of chunks along S
#define CL 32                   // chunk length (CH*CL == SS)
#define BND (BB*NSTATE*HIDDEN)  // 32768
#define LOG2E 1.44269504088896f

#define RT 64                   // rows per k1 block
#define KSPL 8                  // K splits in k1

// ---------------- K1: partial xp = x @ W_xproj, K-split ----------------
// grid 512 = 64 row-tiles x 8 k-splits; block 256 (16 col-groups x 16 row-groups)
// each thread: 4 rows x 6 cols over a K range of 128.
__global__ __launch_bounds__(256) void k_xproj2(const float* __restrict__ x,
                                                const float* __restrict__ W,
                                                float* __restrict__ part) {
    __shared__ float xs[RT * 32];      // [row][kb^swz] float4 blocks, 8KB
    __shared__ float wt[96 * 36];      // transposed W [c][k], stride 36, 13.5KB
    int t  = threadIdx.x;
    int rt = blockIdx.x >> 3;
    int ks = blockIdx.x & 7;
    int r0 = rt * RT;
    int k0 = ks * 128;
    int cg = t & 15, rg = t >> 4;

    float acc[4][6];
    #pragma unroll
    for (int a = 0; a < 4; ++a)
        #pragma unroll
        for (int b = 0; b < 6; ++b) acc[a][b] = 0.f;

    for (int ch = 0; ch < 4; ++ch) {
        int kc = k0 + ch * 32;
        __syncthreads();
        // stage x tile: 64 rows x 32 k, swizzled 16B blocks
        #pragma unroll
        for (int m = 0; m < 2; ++m) {
            int e = t + m * 256;
            int row = e >> 3, kb = e & 7;
            float4 v = *(const float4*)&x[(r0 + row) * HIDDEN + kc + kb * 4];
            int kbp = kb ^ ((row >> 2) & 7);
            *(float4*)&xs[row * 32 + kbp * 4] = v;
        }
        // stage W tile transposed: 32 k x 96 c -> wt[c][k]
        #pragma unroll
        for (int m = 0; m < 3; ++m) {
            int f = t + m * 256;
            int kr = f / 24, cq = f % 24;
            float4 v = *(const float4*)&W[(kc + kr) * XPC + cq * 4];
            wt[(cq * 4 + 0) * 36 + kr] = v.x;
            wt[(cq * 4 + 1) * 36 + kr] = v.y;
            wt[(cq * 4 + 2) * 36 + kr] = v.z;
            wt[(cq * 4 + 3) * 36 + kr] = v.w;
        }
        __syncthreads();
        #pragma unroll
        for (int kg = 0; kg < 8; ++kg) {
            float4 wv[6], xv[4];
            #pragma unroll
            for (int j = 0; j < 6; ++j)
                wv[j] = *(float4*)&wt[(cg + 16 * j) * 36 + kg * 4];
            #pragma unroll
            for (int rr = 0; rr < 4; ++rr) {
                int row = rg * 4 + rr;
                xv[rr] = *(float4*)&xs[row * 32 + ((kg ^ ((row >> 2) & 7)) * 4)];
            }
            #pragma unroll
            for (int rr = 0; rr < 4; ++rr)
                #pragma unroll
                for (int j = 0; j < 6; ++j) {
                    acc[rr][j] = fmaf(xv[rr].x, wv[j].x, acc[rr][j]);
                    acc[rr][j] = fmaf(xv[rr].y, wv[j].y, acc[rr][j]);
                    acc[rr][j] = fmaf(xv[rr].z, wv[j].z, acc[rr][j]);
                    acc[rr][j] = fmaf(xv[rr].w, wv[j].w, acc[rr][j]);
                }
        }
    }
    #pragma unroll
    for (int rr = 0; rr < 4; ++rr)
        #pragma unroll
        for (int j = 0; j < 6; ++j)
            part[ks * (ROWS * XPC) + (r0 + rg * 4 + rr) * XPC + cg + 16 * j] = acc[rr][j];
}

// ---------------- K2: fused reduce(part)->xp  +  dt = softplus(xp_dt @ W_dt + b) ----------------
// 8 rows per block; 512 blocks
__global__ void k_rdt(const float* __restrict__ part, const float* __restrict__ Wdt,
                      const float* __restrict__ bdt, float* __restrict__ xp,
                      float* __restrict__ dt) {
    __shared__ float xs[8 * 64];
    int t = threadIdx.x;
    int r0 = blockIdx.x * 8;
    #pragma unroll
    for (int m = 0; m < 3; ++m) {
        int o = t + m * 256;              // 0..767
        int row = o / 96, col = o % 96;
        float s = 0.f;
        #pragma unroll
        for (int p = 0; p < KSPL; ++p)
            s += part[p * (ROWS * XPC) + (r0 + row) * XPC + col];
        xp[(r0 + row) * XPC + col] = s;
        if (col >= 2 * NSTATE) xs[row * 64 + (col - 2 * NSTATE)] = s;
    }
    __syncthreads();
    float4 acc[8];
    float4 b = *(const float4*)&bdt[t * 4];
    #pragma unroll
    for (int rr = 0; rr < 8; ++rr) acc[rr] = b;
    #pragma unroll 4
    for (int k = 0; k < DTRANK; ++k) {
        float4 w = *(const float4*)&Wdt[k * HIDDEN + t * 4];
        #pragma unroll
        for (int rr = 0; rr < 8; ++rr) {
            float s = xs[rr * 64 + k];
            acc[rr].x = fmaf(s, w.x, acc[rr].x);
            acc[rr].y = fmaf(s, w.y, acc[rr].y);
            acc[rr].z = fmaf(s, w.z, acc[rr].z);
            acc[rr].w = fmaf(s, w.w, acc[rr].w);
        }
    }
    #pragma unroll
    for (int rr = 0; rr < 8; ++rr) {
        float4 a = acc[rr], o;
        o.x = fmaxf(a.x, 0.f) + log1pf(__expf(-fabsf(a.x)));
        o.y = fmaxf(a.y, 0.f) + log1pf(__expf(-fabsf(a.y)));
        o.z = fmaxf(a.z, 0.f) + log1pf(__expf(-fabsf(a.z)));
        o.w = fmaxf(a.w, 0.f) + log1pf(__expf(-fabsf(a.w)));
        *(float4*)&dt[(r0 + rr) * HIDDEN + t * 4] = o;
    }
}

// ---------------- K3 (pass 1): thread owns (c,b,d), all 16 states in regs ----------------
// grid = CH*BB*4 = 512 blocks
__global__ __launch_bounds__(256, 4)
void k_pass1(const float* __restrict__ x, const float* __restrict__ dt,
             const float* __restrict__ xp, const float* __restrict__ Alog,
             float* __restrict__ P, float* __restrict__ Q) {
    int bid = blockIdx.x;
    int dblk = bid & 3;
    int b = (bid >> 2) & 1;
    int c = bid >> 3;
    int d = dblk * 256 + threadIdx.x;
    float A2[NSTATE], Pv[NSTATE], Qv[NSTATE];
    #pragma unroll
    for (int n = 0; n < NSTATE; ++n) {
        A2[n] = -__expf(Alog[n*HIDDEN + d]) * LOG2E;
        Pv[n] = 1.f; Qv[n] = 0.f;
    }
    int s0 = c * CL;
    for (int i = 0; i < CL; ++i) {
        int r = b*SS + s0 + i;
        float dv = dt[r*HIDDEN + d];
        float xv = x[r*HIDDEN + d];
        float bm[NSTATE];
        *(float4*)&bm[0]  = *(const float4*)&xp[r*XPC + 0];
        *(float4*)&bm[4]  = *(const float4*)&xp[r*XPC + 4];
        *(float4*)&bm[8]  = *(const float4*)&xp[r*XPC + 8];
        *(float4*)&bm[12] = *(const float4*)&xp[r*XPC + 12];
        float bx = dv * xv;
        #pragma unroll
        for (int n = 0; n < NSTATE; ++n) {
            float a = exp2f(A2[n] * dv);
            Qv[n] = fmaf(a, Qv[n], bm[n] * bx);
            Pv[n] *= a;
        }
    }
    int base = b*(NSTATE*HIDDEN) + d;
    #pragma unroll
    for (int n = 0; n < NSTATE; ++n) {
        P[c*BND + base + n*HIDDEN] = Pv[n];
        Q[c*BND + base + n*HIDDEN] = Qv[n];
    }
}

// ---------------- K4 (pass 2): serial scan over chunks, 8-deep batched loads ----------------
__global__ void k_pass2(float* __restrict__ P, const float* __restrict__ Q) {
    int bnd = blockIdx.x * 256 + threadIdx.x;   // < 32768
    float h = 0.f;
    for (int cb = 0; cb < CH / 8; ++cb) {
        float p[8], q[8];
        #pragma unroll
        for (int j = 0; j < 8; ++j) {
            int idx = (cb*8 + j)*BND + bnd;
            p[j] = P[idx]; q[j] = Q[idx];
        }
        #pragma unroll
        for (int j = 0; j < 8; ++j) {
            int idx = (cb*8 + j)*BND + bnd;
            P[idx] = h;                 // h_start for chunk
            h = fmaf(p[j], h, q[j]);
        }
    }
}

// ---------------- K5 (pass 3): re-run local scan from h_start, emit y ----------------
// grid = CH*BB*4 = 512 blocks
__global__ __launch_bounds__(256, 4)
void k_pass3(const float* __restrict__ x, const float* __restrict__ dt,
             const float* __restrict__ xp, const float* __restrict__ Alog,
             const float* __restrict__ Hs, float* __restrict__ y) {
    int bid = blockIdx.x;
    int dblk = bid & 3;
    int b = (bid >> 2) & 1;
    int c = bid >> 3;
    int d = dblk * 256 + threadIdx.x;

    float A2[NSTATE], h[NSTATE];
    #pragma unroll
    for (int n = 0; n < NSTATE; ++n) {
        A2[n] = -__expf(Alog[n*HIDDEN + d]) * LOG2E;
        h[n] = Hs[c*BND + b*(NSTATE*HIDDEN) + n*HIDDEN + d];
    }
    int s0 = c * CL;
    for (int i = 0; i < CL; ++i) {
        int r = b*SS + s0 + i;
        float dv = dt[r*HIDDEN + d];
        float xv = x[r*HIDDEN + d];
        float bx = dv * xv;
        float bm[NSTATE], cm[NSTATE];
        *(float4*)&bm[0]  = *(const float4*)&xp[r*XPC + 0];
        *(float4*)&bm[4]  = *(const float4*)&xp[r*XPC + 4];
        *(float4*)&bm[8]  = *(const float4*)&xp[r*XPC + 8];
        *(float4*)&bm[12] = *(const float4*)&xp[r*XPC + 12];
        *(float4*)&cm[0]  = *(const float4*)&xp[r*XPC + 16];
        *(float4*)&cm[4]  = *(const float4*)&xp[r*XPC + 20];
        *(float4*)&cm[8]  = *(const float4*)&xp[r*XPC + 24];
        *(float4*)&cm[12] = *(const float4*)&xp[r*XPC + 28];
        float yv = 0.f;
        #pragma unroll
        for (int n = 0; n < NSTATE; ++n) {
            float a = exp2f(A2[n] * dv);
            h[n] = fmaf(a, h[n], bm[n] * bx);
            yv = fmaf(cm[n], h[n], yv);
        }
        y[r*HIDDEN + d] = yv;
    }
}

extern "C" void kernel_launch(void* const* d_in, const int* in_sizes, int n_in,
                              void* d_out, int out_size, void* d_ws, size_t ws_size,
                              hipStream_t stream) {
    const float* x    = (const float*)d_in[0];
    const float* Wx   = (const float*)d_in[1];
    const float* Wdt  = (const float*)d_in[2];
    const float* bdt  = (const float*)d_in[3];
    const float* Alog = (const float*)d_in[4];
    float* y  = (float*)d_out;
    float* ws = (float*)d_ws;

    float* xp = ws;                       // 393216 floats
    float* dt = xp + ROWS*XPC;            // 4194304 floats
    float* A  = dt + ROWS*HIDDEN;         // alias region:
    float* part = A;                      //   k1 partials: 3145728 floats (12.6MB)
    float* P  = A;                        //   P: CH*BND = 2097152 floats (8.4MB)
    float* Q  = A + CH*BND;               //   Q: 2097152 floats (8.4MB)
    // total ws use: ~35 MB

    k_xproj2<<<(ROWS/RT)*KSPL, 256, 0, stream>>>(x, Wx, part);
    k_rdt<<<ROWS/8, 256, 0, stream>>>(part, Wdt, bdt, xp, dt);
    k_pass1<<<CH*BB*4, 256, 0, stream>>>(x, dt, xp, Alog, P, Q);
    k_pass2<<<BND/256, 256, 0, stream>>>(P, Q);
    k_pass3<<<CH*BB*4, 256, 0, stream>>>(x, dt, xp, Alog, P, y);
}